// Round 9
// baseline (193.759 us; speedup 1.0000x reference)
//
#include <hip/hip_runtime.h>

// TT embedding lookup, grouped by (table, i1). R9: LINEAR-STREAM main —
// core1 is read as one globally-sequential 113 MB stream (chunk c <->
// bytes [32c KB, 32(c+1) KB)), XCD-swizzled so each XCD walks a contiguous
// 14 MB span. Per-chunk math = R6's verified geometry; partials combined
// into out via atomicAdd (out pre-zeroed).
// P=(216,216,216), Q=(2,4,2), R=(128,128), tables=2, batch=1024.
// core0: [2,216,256]   (A row:  [Q0=2][R0=128])
// core1: [2,216,65536] (Bm row: [R0=128][S=512], S = q1*128 + r1)
// core2: [2,216,256]   (C row:  [R1=128][Q2=2])
// out:   [2,1024,16]   (flat per lookup: q0*8 + q1*2 + j)
//
// d_ws int layout:
//   [0,432)      group start offsets
//   [432,864)    group counts
//   [864,2912)   sorted lookup ids (counting sort by group)
//   [2912,4960)  per-lookup aux: (i0<<16)|i2

#define NGROUPS 432
#define NLOOK   2048

typedef float f4 __attribute__((ext_vector_type(4)));

__global__ __launch_bounds__(512) void tt_prep(const int* __restrict__ idx32,
                                               int* __restrict__ w) {
    __shared__ int cnt[NGROUPS];
    __shared__ int wtot[8];
    __shared__ int cursor[NGROUPS];
    const int tid  = threadIdx.x;
    const int lane = tid & 63;
    const int wv   = tid >> 6;

    for (int i = tid; i < NGROUPS; i += 512) cnt[i] = 0;
    __syncthreads();

    // int64-vs-int32 buffer detection (values < 2^31 => odd words zero in LE int64)
    const bool is64 = (idx32[1] == 0) & (idx32[3] == 0) &
                      (idx32[5] == 0) & (idx32[7] == 0);

    int grp[4];
#pragma unroll
    for (int j = 0; j < 4; ++j) {
        const int id = tid + j * 512;
        const unsigned idx = is64 ? (unsigned)((const long long*)idx32)[id]
                                  : (unsigned)idx32[id];
        const unsigned i0  = idx / 46656u;
        const unsigned rem = idx - i0 * 46656u;
        const unsigned i1  = rem / 216u;
        const unsigned i2  = rem - i1 * 216u;
        const int table = id >> 10;
        grp[j] = table * 216 + (int)i1;
        w[2912 + id] = (int)((i0 << 16) | i2);
        atomicAdd(&cnt[grp[j]], 1);
    }
    __syncthreads();

    // two-level exclusive scan: shfl wave-scan + wave-total offsets
    const int v = (tid < NGROUPS) ? cnt[tid] : 0;
    int s = v;
#pragma unroll
    for (int d = 1; d < 64; d <<= 1) {
        const int t = __shfl_up(s, d);
        if (lane >= d) s += t;
    }
    if (lane == 63) wtot[wv] = s;
    __syncthreads();
    int off = 0;
    for (int i = 0; i < wv; ++i) off += wtot[i];
    if (tid < NGROUPS) {
        const int st = s + off - v;        // exclusive prefix
        w[tid]       = st;
        w[432 + tid] = v;
        cursor[tid]  = st;
    }
    __syncthreads();

#pragma unroll
    for (int j = 0; j < 4; ++j) {
        const int id  = tid + j * 512;
        const int pos = atomicAdd(&cursor[grp[j]], 1);
        w[864 + pos] = id;
    }
}

// 3456 blocks x 256 threads. Block b -> chunk c = (b&7)*432 + (b>>3) so XCD
// (b%8) walks a contiguous 14 MB span; chunk c = group g=c>>3, row-block
// rb=c&7 (rows [16rb,16rb+16)), i.e. core1 bytes [32c KB, 32(c+1) KB).
__global__ __launch_bounds__(256) void tt_main(
    const float* __restrict__ c0,
    const float* __restrict__ c1,
    const float* __restrict__ c2,
    const int* __restrict__ w,
    float* __restrict__ out)
{
    const int c  = ((int)blockIdx.x & 7) * 432 + ((int)blockIdx.x >> 3);
    const int g  = c >> 3;          // group id [0,432)
    const int rb = c & 7;           // row-block: rows [16rb, 16rb+16)
    const int m = w[432 + g];
    if (m == 0) return;
    const int s0    = w[g];
    const int table = g / 216;

    const int t      = threadIdx.x;
    const int h      = t >> 7;        // row parity within each 2-row sweep
    const int lane31 = t & 31;
    const int q1     = (t >> 5) & 3;  // this thread's q1 (col block)

    __shared__ float A_s[8][16][2];   // [l][r_local][q0] (wave-broadcast reads)
    __shared__ float comb[8][36];     // [(h*4+q1)][l*4+q0*2+j], padded stride
    __shared__ int s_id[8];
    __shared__ int s_aux[8];

    // The block's 32 KB = 8 contiguous 4 KB sweeps; thread's cols = 4*(t&127),
    // rows 2i+h. Issue ALL 8 nontemporal dwordx4 loads up front; b[] persists
    // in registers across lookup-tiles.
    const f4* bp = (const f4*)c1 + (size_t)c * 2048 + t;
    f4 b[8];
#pragma unroll
    for (int i = 0; i < 8; ++i)
        b[i] = __builtin_nontemporal_load(bp + i * 256);

    const float* c0t = c0 + (size_t)table * 216 * 256;
    const float* c2t = c2 + (size_t)table * 216 * 256;
    const int r1 = 4 * lane31;        // col within q1 block

    for (int base = 0; base < m; base += 8) {
        const int cl = min(8, m - base);
        if (base) __syncthreads();    // protect s_*/A_s rewrite vs prior tile
        if (t < 8) {
            const bool ok = t < cl;
            const int id  = ok ? w[864 + s0 + base + t] : 0;
            s_id[t]  = id;
            s_aux[t] = ok ? w[2912 + id] : 0;   // pad -> row 0, output gated
        }
        __syncthreads();

        // stage this row-block's A slice: 8l x 16r x 2q0 = 256 floats
        {
            const int l = t >> 5, e = t & 31;
            const int rl = e >> 1, q0 = e & 1;
            A_s[l][rl][q0] =
                c0t[(size_t)(s_aux[l] >> 16) * 256 + q0 * 128 + rb * 16 + rl];
        }
        __syncthreads();

        f4 wacc[8][2];                // [l][q0]
#pragma unroll
        for (int l = 0; l < 8; ++l) { wacc[l][0] = (f4)0.f; wacc[l][1] = (f4)0.f; }

#pragma unroll
        for (int i = 0; i < 8; ++i) {
            const int rl = 2 * i + h;
#pragma unroll
            for (int l = 0; l < 8; ++l) {
                wacc[l][0] += A_s[l][rl][0] * b[i];
                wacc[l][1] += A_s[l][rl][1] * b[i];
            }
        }

        // per-l: C contraction on this r-slice partial (linear => valid),
        // software-pipelined C loads, 32-lane butterfly, one writer per (h,q1)
        f4 cA = *(const f4*)(c2t + (size_t)(s_aux[0] & 0xffff) * 256 + 2 * r1);
        f4 cB = *(const f4*)(c2t + (size_t)(s_aux[0] & 0xffff) * 256 + 2 * r1 + 4);
#pragma unroll
        for (int l = 0; l < 8; ++l) {
            const f4 curA = cA, curB = cB;
            if (l + 1 < 8) {
                const float* crow = c2t + (size_t)(s_aux[l + 1] & 0xffff) * 256 + 2 * r1;
                cA = *(const f4*)crow;
                cB = *(const f4*)(crow + 4);
            }
            if (l < cl) {
                float p00 = wacc[l][0].x*curA.x + wacc[l][0].y*curA.z + wacc[l][0].z*curB.x + wacc[l][0].w*curB.z;
                float p01 = wacc[l][0].x*curA.y + wacc[l][0].y*curA.w + wacc[l][0].z*curB.y + wacc[l][0].w*curB.w;
                float p10 = wacc[l][1].x*curA.x + wacc[l][1].y*curA.z + wacc[l][1].z*curB.x + wacc[l][1].w*curB.z;
                float p11 = wacc[l][1].x*curA.y + wacc[l][1].y*curA.w + wacc[l][1].z*curB.y + wacc[l][1].w*curB.w;
#pragma unroll
                for (int mm = 16; mm >= 1; mm >>= 1) {
                    p00 += __shfl_xor(p00, mm);
                    p01 += __shfl_xor(p01, mm);
                    p10 += __shfl_xor(p10, mm);
                    p11 += __shfl_xor(p11, mm);
                }
                if (lane31 == 0) {
                    float* cb = &comb[h * 4 + q1][l * 4];
                    cb[0] = p00; cb[1] = p01; cb[2] = p10; cb[3] = p11;
                }
            }
        }
        __syncthreads();

        // combine h-halves, atomically add this row-block's contribution
        if (t < 16 * cl) {
            const int l = t >> 4, k = t & 15;          // k = q0*8 + q1*2 + j
            const int q0 = k >> 3, qq = (k >> 1) & 3, j = k & 1;
            const float v = comb[qq][l * 4 + q0 * 2 + j] +
                            comb[4 + qq][l * 4 + q0 * 2 + j];
            atomicAdd(&out[(size_t)s_id[l] * 16 + k], v);
        }
    }
}

extern "C" void kernel_launch(void* const* d_in, const int* in_sizes, int n_in,
                              void* d_out, int out_size, void* d_ws, size_t ws_size,
                              hipStream_t stream) {
    const int*   idx = (const int*)d_in[0];
    const float* c0  = (const float*)d_in[1];
    const float* c1  = (const float*)d_in[2];
    const float* c2  = (const float*)d_in[3];
    float* out = (float*)d_out;
    int* w = (int*)d_ws;

    hipMemsetAsync(out, 0, (size_t)out_size * sizeof(float), stream);
    tt_prep<<<dim3(1), dim3(512), 0, stream>>>(idx, w);
    tt_main<<<dim3(8 * NGROUPS), dim3(256), 0, stream>>>(c0, c1, c2, w, out);
}